// Round 15
// baseline (172.188 us; speedup 1.0000x reference)
//
#include <hip/hip_runtime.h>
#include <hip/hip_bf16.h>
#include <math.h>

using bf16 = __hip_bfloat16;
typedef __attribute__((ext_vector_type(8))) short bf16x8;
typedef __attribute__((ext_vector_type(4))) short bf16x4;
typedef __attribute__((ext_vector_type(4))) float f32x4;
typedef __attribute__((ext_vector_type(2))) int i32x2;

// async global->LDS, 16B per lane (guide §5: width=16 is the m93->m97 2x step)
static __device__ __forceinline__ void gl_lds16(const void* g, void* l) {
  __builtin_amdgcn_global_load_lds(
      (const __attribute__((address_space(1))) unsigned int*)g,
      (__attribute__((address_space(3))) unsigned int*)l, 16, 0, 0);
}

#define MFMA16 __builtin_amdgcn_mfma_f32_16x16x32_bf16
#define MFMA16K16 __builtin_amdgcn_mfma_f32_16x16x16bf16_1k

// fast f32->bf16 (round-to-nearest-ish; fine for p in [0,1] and O outputs)
static __device__ __forceinline__ short f2bf(float f) {
  return (short)((__builtin_bit_cast(unsigned int, f) + 0x8000u) >> 16);
}

// ---------------------------------------------------------------------------
// Kernel 0: fp32 -> bf16 for all three inputs in ONE launch.
// grid 8192: [0,4096) x, [4096,7168) Wqkv, [7168,8192) Wout.
// ---------------------------------------------------------------------------
__global__ __launch_bounds__(256) void cvt_all(
    const float* __restrict__ x, const float* __restrict__ wqkv,
    const float* __restrict__ wout, bf16* __restrict__ xb,
    bf16* __restrict__ wqkvb, bf16* __restrict__ woutb) {
  const int blk = blockIdx.x;
  const float* src;
  bf16* dst;
  int base;
  if (blk < 4096) {
    src = x; dst = xb; base = blk;
  } else if (blk < 7168) {
    src = wqkv; dst = wqkvb; base = blk - 4096;
  } else {
    src = wout; dst = woutb; base = blk - 7168;
  }
  const int i = (base * 256 + threadIdx.x) * 4;
  const float4 v = *(const float4*)(src + i);
  bf16x4 o;
  o.x = f2bf(v.x);
  o.y = f2bf(v.y);
  o.z = f2bf(v.z);
  o.w = f2bf(v.w);
  *(bf16x4*)(dst + i) = o;
}

// ---------------------------------------------------------------------------
// 128x128 block of C[m,n] = sum_k A[m,k]*B[n,k]   (A:[*,K] row-major, B:[*,K])
// R14: BK=64, XOR-swizzled LDS (pos^(row&7)) on both stage-source and read.
// ---------------------------------------------------------------------------
template <int K>
static __device__ __forceinline__ void gemm_bt_acc(
    const bf16* __restrict__ A, const bf16* __restrict__ B,
    int rowA0, int rowB0, bf16* As, bf16* Bs, f32x4 acc[4][4]) {
  const int t = threadIdx.x;
  const int w = t >> 6, l = t & 63;
  const int quad = l >> 4, l16 = l & 15;
  const int wm = (w >> 1) * 64, wn = (w & 1) * 64;
  for (int k0 = 0; k0 < K; k0 += 64) {
    __syncthreads();
#pragma unroll
    for (int ii = 0; ii < 4; ii++) {
      const int c = t + ii * 256;  // 0..1023: row = c>>3 (128B rows), pos 0..7
      const int row = c >> 3, pos = c & 7;
      const size_t off = (size_t)row * K + k0 + ((pos ^ (row & 7)) * 8);
      gl_lds16(A + (size_t)rowA0 * K + off, As + c * 8);
      gl_lds16(B + (size_t)rowB0 * K + off, Bs + c * 8);
    }
    __syncthreads();
#pragma unroll
    for (int kk2 = 0; kk2 < 2; kk2++) {
      bf16x8 af[4], bg[4];
#pragma unroll
      for (int i = 0; i < 4; i++) {
        const int rr = wm + i * 16 + l16;  // rr&7 == l16&7
        const int ci = (kk2 * 4 + quad) ^ (l16 & 7);
        af[i] = *(const bf16x8*)(As + rr * 64 + ci * 8);
      }
#pragma unroll
      for (int j = 0; j < 4; j++) {
        const int rr = wn + j * 16 + l16;
        const int ci = (kk2 * 4 + quad) ^ (l16 & 7);
        bg[j] = *(const bf16x8*)(Bs + rr * 64 + ci * 8);
      }
#pragma unroll
      for (int i = 0; i < 4; i++)
#pragma unroll
        for (int j = 0; j < 4; j++)
          acc[i][j] = MFMA16(af[i], bg[j], acc[i][j], 0, 0, 0);
    }
  }
}

// ---------------------------------------------------------------------------
// Kernel 1: qkv = x @ Wqkv^T ; scatter Q*0.125 (pre-scaled), K, Vt.
// Grid dim3(32,24): default order is XCD-optimal (XCD = bm%8 keeps its 4
// A-panels L2-resident; R13's chunked swizzle broke this, +6us).
// ---------------------------------------------------------------------------
__global__ __launch_bounds__(256, 3) void qkv_gemm(
    const bf16* __restrict__ x, const bf16* __restrict__ Wqkv,
    bf16* __restrict__ Qb, bf16* __restrict__ Kb, bf16* __restrict__ Vt) {
  __shared__ bf16 As[128 * 64];
  __shared__ bf16 Bs[128 * 64];
  f32x4 acc[4][4];
#pragma unroll
  for (int i = 0; i < 4; i++)
#pragma unroll
    for (int j = 0; j < 4; j++) acc[i][j] = (f32x4){0.f, 0.f, 0.f, 0.f};
  const int bm = blockIdx.x, bn = blockIdx.y;
  gemm_bt_acc<1024>(x, Wqkv, bm * 128, bn * 128, As, Bs, acc);

  const int t = threadIdx.x, w = t >> 6, l = t & 63;
  const int quad = l >> 4, l16 = l & 15;
  const int wm = (w >> 1) * 64, wn = (w & 1) * 64;
#pragma unroll
  for (int i = 0; i < 4; i++) {
    const int m0 = bm * 128 + wm + i * 16 + quad * 4;  // 4 contiguous m (=s)
    const int b = m0 >> 11, s0 = m0 & 2047;            // same b for all 4 r
#pragma unroll
    for (int j = 0; j < 4; j++) {
      const int n = bn * 128 + wn + j * 16 + l16;  // 0..3071
      const int which = n >> 10;
      const int nn = n & 1023;
      const int h = nn >> 6, d = nn & 63;
      const int bh = b * 16 + h;
      if (which == 2) {  // V: contiguous s -> one vectorized store
        bf16x4 v4;
#pragma unroll
        for (int r = 0; r < 4; r++)
          v4[r] = (short)__builtin_bit_cast(unsigned short,
                                            __float2bfloat16(acc[i][j][r]));
        *(bf16x4*)(Vt + ((size_t)bh * 64 + d) * 2048 + s0) = v4;
      } else {
        const float sc = (which == 0) ? 0.125f : 1.0f;  // fold softmax scale
        bf16* dst = (which == 0) ? Qb : Kb;
#pragma unroll
        for (int r = 0; r < 4; r++)
          dst[((size_t)bh * 2048 + s0 + r) * 64 + d] =
              __float2bfloat16(acc[i][j][r] * sc);
      }
    }
  }
}

// ---------------------------------------------------------------------------
// Kernel 2: causal flash attention — R6 inner loop EXACTLY; R15: SPLIT-K for
// the long half (flash-decoding). The session's one validated model: wall ~
// (34 tiles/CU x 2.6us)/C, C = concurrency ~ sum/max of resident block
// lengths (22% occ -> C~2.1 -> 42us). Fix imbalance WITHOUT adding tiles:
// qt>=16 is processed by TWO independent partial blocks (4-8 tiles each;
// softmax is additive so the k-split is exact); partial f32 O + denominator
// go to workspace; attn_combine sums+normalizes. Grid 1536 (6 dispatched/CU
// vs 4 resident -> real backfill), max block 16->9 tiles, ~LPT order.
// ---------------------------------------------------------------------------
__global__ __launch_bounds__(256, 4) void attn_kernel(
    const bf16* __restrict__ Qb, const bf16* __restrict__ Kb,
    const bf16* __restrict__ Vt, bf16* __restrict__ attn,
    float* __restrict__ Opart, float* __restrict__ lpart) {
  __shared__ bf16 Ks[128 * 64];   // [krow][d]  swizzled (8 chunks/row)
  __shared__ bf16 Vts[64 * 128];  // [d][s]     swizzled (16 chunks/row)
  const int x = blockIdx.x;
  const int bh = x & 31;
  const int u = x >> 5;  // 0..47, ~LPT: long split-halves first, then shorts
  const bool split = u < 32;
  const int qt = split ? 31 - (u >> 1) : 47 - u;  // split: 31..16; short: 15..0
  const int sp = split ? (u & 1) : 0;
  const int q0 = qt * 64;
  const int t = threadIdx.x, w = t >> 6, l = t & 63;
  const int quad = l >> 4, l16 = l & 15;
  const bf16x4 ones = {16256, 16256, 16256, 16256};  // bf16 1.0 x4
  const int b = bh >> 4, h = bh & 15;

  // ---- Q into registers: lane holds Q[q=qrow][d=kk*32+quad*8+e] ----
  const int qrow = q0 + w * 16 + l16;
  const bf16* Qg = Qb + ((size_t)bh * 2048 + qrow) * 64 + quad * 8;
  bf16x8 qreg[2];
  qreg[0] = *(const bf16x8*)(Qg);
  qreg[1] = *(const bf16x8*)(Qg + 32);

  f32x4 oacc[4];  // [md d-16]; O^T: q=l16, d=quad*4+reg
  f32x4 lacc = (f32x4){0.f, 0.f, 0.f, 0.f};  // ones·P = denominator (partial)
#pragma unroll
  for (int md = 0; md < 4; md++) oacc[md] = (f32x4){0.f, 0.f, 0.f, 0.f};

  const int njj = (qt + 2) >> 1;  // 128-wide tiles covering cols 0..q0+63
  const int njj0 = njj >> 1;      // split point (only used when split)
  int jlo = 0, jhi = njj;
  if (split) {
    if (sp) jlo = njj0;
    else jhi = njj0;  // sp=0 half never reaches the masked last tile
  }
  for (int jj = jlo; jj < jhi; jj++) {
    const int j0 = jj * 128;
    __syncthreads();  // prior iter's Ks/Vts reads complete
    const bf16* Kg = Kb + ((size_t)bh * 2048 + j0) * 64;
#pragma unroll
    for (int c = t; c < 1024; c += 256) {
      const int row = c >> 3, pos = c & 7;
      gl_lds16(Kg + (row * 8 + (pos ^ (row & 7))) * 8, Ks + c * 8);
    }
    const bf16* Vg = Vt + (size_t)bh * 64 * 2048 + j0;
#pragma unroll
    for (int c = t; c < 1024; c += 256) {
      const int d = c >> 4, pos = c & 15;
      gl_lds16(Vg + (size_t)d * 2048 + ((pos ^ (d & 15)) * 8), Vts + c * 8);
    }
    __syncthreads();  // staging visible

    // ---- S^T = K Q^T : A=K[s][d] (M=128), B=Q^T[d][q] (N=16 of wave) ----
    f32x4 sacc[8];  // [mt s-16];  C-layout: q=l16, s=quad*4+reg
#pragma unroll
    for (int mt = 0; mt < 8; mt++) sacc[mt] = (f32x4){0.f, 0.f, 0.f, 0.f};
#pragma unroll
    for (int kk = 0; kk < 2; kk++) {
#pragma unroll
      for (int mt = 0; mt < 8; mt++) {
        const int row = mt * 16 + l16;
        const int pos = (kk * 4 + quad) ^ (l16 & 7);  // row&7 == l16&7
        bf16x8 kf = *(const bf16x8*)(Ks + row * 64 + pos * 8);
        sacc[mt] = MFMA16(kf, qreg[kk], sacc[mt], 0, 0, 0);
      }
    }

    // ---- P^T = exp(S^T) packed via v_perm (B-frag layout) ----
    bf16x4 pfrag[8];      // [kt = s-16-block]
    if (jj == njj - 1) {  // wave-uniform: only the last tile masks
#pragma unroll
      for (int mt = 0; mt < 8; mt++) {
        unsigned rb[4];
#pragma unroll
        for (int r2 = 0; r2 < 4; r2++) {
          const int sg = j0 + mt * 16 + quad * 4 + r2;
          const float p = (sg <= qrow) ? __expf(sacc[mt][r2]) : 0.f;
          rb[r2] = __builtin_bit_cast(unsigned, p) + 0x8000u;
        }
        i32x2 pk;
        pk.x = (int)__builtin_amdgcn_perm(rb[1], rb[0], 0x07060302u);
        pk.y = (int)__builtin_amdgcn_perm(rb[3], rb[2], 0x07060302u);
        pfrag[mt] = __builtin_bit_cast(bf16x4, pk);
      }
    } else {
#pragma unroll
      for (int mt = 0; mt < 8; mt++) {
        unsigned rb[4];
#pragma unroll
        for (int r2 = 0; r2 < 4; r2++) {
          const float p = __expf(sacc[mt][r2]);
          rb[r2] = __builtin_bit_cast(unsigned, p) + 0x8000u;
        }
        i32x2 pk;
        pk.x = (int)__builtin_amdgcn_perm(rb[1], rb[0], 0x07060302u);
        pk.y = (int)__builtin_amdgcn_perm(rb[3], rb[2], 0x07060302u);
        pfrag[mt] = __builtin_bit_cast(bf16x4, pk);
      }
    }

    // ---- O^T += V^T P^T ; lacc += ones·P^T (denominator in MFMA pipe) ----
#pragma unroll
    for (int kt = 0; kt < 8; kt++) {
      lacc = MFMA16K16(ones, pfrag[kt], lacc, 0, 0, 0);
#pragma unroll
      for (int md = 0; md < 4; md++) {
        const int d = md * 16 + l16;
        const int pos = (kt * 2 + (quad >> 1)) ^ l16;  // d&15 == l16
        bf16x4 va = *(const bf16x4*)(Vts + d * 128 + pos * 8 + (quad & 1) * 4);
        oacc[md] = MFMA16K16(va, pfrag[kt], oacc[md], 0, 0, 0);
      }
    }
  }

  if (!split) {
    // ---- epilogue: every lane holds its q's full denominator ----
    const float inv = 1.0f / lacc[0];
#pragma unroll
    for (int md = 0; md < 4; md++) {
      bf16x4 o4;
#pragma unroll
      for (int r2 = 0; r2 < 4; r2++) o4[r2] = f2bf(oacc[md][r2] * inv);
      *(bf16x4*)(attn + ((size_t)b * 2048 + qrow) * 1024 + h * 64 + md * 16 +
                 quad * 4) = o4;
    }
  } else {
    // ---- partial epilogue: raw f32 O and denominator to workspace ----
    // Opart layout [2][32][1024][64] f32; rows are qrow-1024 (qt>=16).
    float* Od =
        Opart + (((size_t)(sp * 32 + bh) * 1024) + (qrow - 1024)) * 64;
#pragma unroll
    for (int md = 0; md < 4; md++)
      *(f32x4*)(Od + md * 16 + quad * 4) = oacc[md];
    if (quad == 0) lpart[(size_t)(sp * 32 + bh) * 1024 + (qrow - 1024)] = lacc[0];
  }
}

// ---------------------------------------------------------------------------
// Kernel 2b: combine the two k-split partials for qt>=16 rows.
// grid 512 = 32 bh x 16 qt-slots; thread t: row = t>>2, 16 d-elems.
// ---------------------------------------------------------------------------
__global__ __launch_bounds__(256) void attn_combine(
    const float* __restrict__ Opart, const float* __restrict__ lpart,
    bf16* __restrict__ attn) {
  const int blk = blockIdx.x;  // 0..511
  const int bh = blk >> 4, qi = blk & 15;  // qt = 16 + qi
  const int t = threadIdx.x;
  const int r = t >> 2, dg = (t & 3) * 16;
  const size_t rowl = (size_t)bh * 1024 + qi * 64 + r;  // row in [32][1024]
  const float l0 = lpart[rowl];
  const float l1 = lpart[(size_t)32 * 1024 + rowl];
  const float inv = 1.0f / (l0 + l1);
  const float* O0 = Opart + rowl * 64 + dg;
  const float* O1 = Opart + (size_t)32 * 1024 * 64 + rowl * 64 + dg;
  const int b = bh >> 4, h = bh & 15;
  const int q = 1024 + qi * 64 + r;
  bf16* dst = attn + ((size_t)b * 2048 + q) * 1024 + h * 64 + dg;
#pragma unroll
  for (int v = 0; v < 4; v++) {
    const f32x4 a = *(const f32x4*)(O0 + v * 4);
    const f32x4 c = *(const f32x4*)(O1 + v * 4);
    bf16x4 o4;
#pragma unroll
    for (int e = 0; e < 4; e++) o4[e] = f2bf((a[e] + c[e]) * inv);
    *(bf16x4*)(dst + v * 4) = o4;
  }
}

// ---------------------------------------------------------------------------
// Kernel 3: out = attn @ Wout^T (fp32 output). 128x64 tiles -> grid (32,16)
// (default order is XCD-optimal: XCD=bm%8 keeps A-panels L2-resident).
// ---------------------------------------------------------------------------
__global__ __launch_bounds__(256) void out_gemm(
    const bf16* __restrict__ attn, const bf16* __restrict__ Wout,
    float* __restrict__ out) {
  __shared__ bf16 As[128 * 32];
  __shared__ bf16 Bs[64 * 32];
  f32x4 acc[4][2];
#pragma unroll
  for (int i = 0; i < 4; i++)
#pragma unroll
    for (int j = 0; j < 2; j++) acc[i][j] = (f32x4){0.f, 0.f, 0.f, 0.f};
  const int bm = blockIdx.x, bn = blockIdx.y;
  const int t = threadIdx.x, w = t >> 6, l = t & 63;
  const int quad = l >> 4, l16 = l & 15;
  const int wm = (w >> 1) * 64, wn = (w & 1) * 32;
  const int c0 = t, c1 = t + 256;
  const bf16* a0 = attn + (size_t)(bm * 128 + (c0 >> 2)) * 1024 + (c0 & 3) * 8;
  const bf16* a1 = attn + (size_t)(bm * 128 + (c1 >> 2)) * 1024 + (c1 & 3) * 8;
  const bf16* b0 = Wout + (size_t)(bn * 64 + (t >> 2)) * 1024 + (t & 3) * 8;
  for (int k0 = 0; k0 < 1024; k0 += 32) {
    __syncthreads();
    gl_lds16(a0 + k0, As + c0 * 8);
    gl_lds16(a1 + k0, As + c1 * 8);
    gl_lds16(b0 + k0, Bs + t * 8);
    __syncthreads();
    bf16x8 af[4], bg[2];
#pragma unroll
    for (int i = 0; i < 4; i++)
      af[i] = *(const bf16x8*)(As + (wm + i * 16 + l16) * 32 + quad * 8);
#pragma unroll
    for (int j = 0; j < 2; j++)
      bg[j] = *(const bf16x8*)(Bs + (wn + j * 16 + l16) * 32 + quad * 8);
#pragma unroll
    for (int i = 0; i < 4; i++)
#pragma unroll
      for (int j = 0; j < 2; j++)
        acc[i][j] = MFMA16(af[i], bg[j], acc[i][j], 0, 0, 0);
  }
#pragma unroll
  for (int i = 0; i < 4; i++) {
#pragma unroll
    for (int j = 0; j < 2; j++) {
      const int n = bn * 64 + wn + j * 16 + l16;
#pragma unroll
      for (int r = 0; r < 4; r++) {
        const int m = bm * 128 + wm + i * 16 + quad * 4 + r;
        out[(size_t)m * 1024 + n] = acc[i][j][r];
      }
    }
  }
}

// ---------------------------------------------------------------------------
extern "C" void kernel_launch(void* const* d_in, const int* in_sizes, int n_in,
                              void* d_out, int out_size, void* d_ws, size_t ws_size,
                              hipStream_t stream) {
  const float* x = (const float*)d_in[0];      // [2,2048,1024] fp32
  const float* Wqkv = (const float*)d_in[1];   // [3072,1024]   fp32
  const float* Wout = (const float*)d_in[2];   // [1024,1024]   fp32
  float* out = (float*)d_out;                  // [2,2048,1024] fp32

  char* ws = (char*)d_ws;
  const size_t MB = 1024 * 1024;
  bf16* xb = (bf16*)(ws + 0 * MB);      // [4096][1024]  8 MB (consumed by qkv)
  bf16* at = (bf16*)(ws + 0 * MB);      // [4096][1024]  8 MB (alias, after qkv)
  bf16* Wqkvb = (bf16*)(ws + 8 * MB);   // [3072][1024]  6 MB
  bf16* Woutb = (bf16*)(ws + 14 * MB);  // [1024][1024]  2 MB
  bf16* Qb = (bf16*)(ws + 16 * MB);     // [32][2048][64] 8 MB (pre-scaled)
  bf16* Kb = (bf16*)(ws + 24 * MB);     // [32][2048][64] 8 MB
  bf16* Vt = (bf16*)(ws + 32 * MB);     // [32][64][2048] 8 MB
  float* Opart = (float*)(ws + 40 * MB);  // [2][32][1024][64] f32, 16.8 MB
  float* lpart = (float*)(ws + 57 * MB);  // [2][32][1024]     f32, 256 KB
  // ws_size = 256 MiB (fill WRITE_SIZE evidence) — 58 MB used, safe.

  cvt_all<<<8192, 256, 0, stream>>>(x, Wqkv, Wout, xb, Wqkvb, Woutb);
  qkv_gemm<<<dim3(32, 24), 256, 0, stream>>>(xb, Wqkvb, Qb, Kb, Vt);
  attn_kernel<<<1536, 256, 0, stream>>>(Qb, Kb, Vt, at, Opart, lpart);
  attn_combine<<<512, 256, 0, stream>>>(Opart, lpart, at);
  out_gemm<<<dim3(32, 16), 256, 0, stream>>>(at, Woutb, out);
}

// Round 16
// 163.598 us; speedup vs baseline: 1.0525x; 1.0525x over previous
//
#include <hip/hip_runtime.h>
#include <hip/hip_bf16.h>
#include <math.h>

using bf16 = __hip_bfloat16;
typedef __attribute__((ext_vector_type(8))) short bf16x8;
typedef __attribute__((ext_vector_type(4))) short bf16x4;
typedef __attribute__((ext_vector_type(4))) float f32x4;
typedef __attribute__((ext_vector_type(2))) int i32x2;

// async global->LDS, 16B per lane (guide §5: width=16 is the m93->m97 2x step)
static __device__ __forceinline__ void gl_lds16(const void* g, void* l) {
  __builtin_amdgcn_global_load_lds(
      (const __attribute__((address_space(1))) unsigned int*)g,
      (__attribute__((address_space(3))) unsigned int*)l, 16, 0, 0);
}

#define MFMA16 __builtin_amdgcn_mfma_f32_16x16x32_bf16
#define MFMA16K16 __builtin_amdgcn_mfma_f32_16x16x16bf16_1k

// fast f32->bf16 (round-to-nearest-ish; fine for p in [0,1] and O outputs)
static __device__ __forceinline__ short f2bf(float f) {
  return (short)((__builtin_bit_cast(unsigned int, f) + 0x8000u) >> 16);
}

// ---------------------------------------------------------------------------
// Kernel 0: fp32 -> bf16 for all three inputs in ONE launch.
// grid 8192: [0,4096) x, [4096,7168) Wqkv, [7168,8192) Wout.
// ---------------------------------------------------------------------------
__global__ __launch_bounds__(256) void cvt_all(
    const float* __restrict__ x, const float* __restrict__ wqkv,
    const float* __restrict__ wout, bf16* __restrict__ xb,
    bf16* __restrict__ wqkvb, bf16* __restrict__ woutb) {
  const int blk = blockIdx.x;
  const float* src;
  bf16* dst;
  int base;
  if (blk < 4096) {
    src = x; dst = xb; base = blk;
  } else if (blk < 7168) {
    src = wqkv; dst = wqkvb; base = blk - 4096;
  } else {
    src = wout; dst = woutb; base = blk - 7168;
  }
  const int i = (base * 256 + threadIdx.x) * 4;
  const float4 v = *(const float4*)(src + i);
  bf16x4 o;
  o.x = f2bf(v.x);
  o.y = f2bf(v.y);
  o.z = f2bf(v.z);
  o.w = f2bf(v.w);
  *(bf16x4*)(dst + i) = o;
}

// ---------------------------------------------------------------------------
// 128x128 block of C[m,n] = sum_k A[m,k]*B[n,k]   (A:[*,K] row-major, B:[*,K])
// R14: BK=64, XOR-swizzled LDS (pos^(row&7)) on both stage-source and read.
// ---------------------------------------------------------------------------
template <int K>
static __device__ __forceinline__ void gemm_bt_acc(
    const bf16* __restrict__ A, const bf16* __restrict__ B,
    int rowA0, int rowB0, bf16* As, bf16* Bs, f32x4 acc[4][4]) {
  const int t = threadIdx.x;
  const int w = t >> 6, l = t & 63;
  const int quad = l >> 4, l16 = l & 15;
  const int wm = (w >> 1) * 64, wn = (w & 1) * 64;
  for (int k0 = 0; k0 < K; k0 += 64) {
    __syncthreads();
#pragma unroll
    for (int ii = 0; ii < 4; ii++) {
      const int c = t + ii * 256;  // 0..1023: row = c>>3 (128B rows), pos 0..7
      const int row = c >> 3, pos = c & 7;
      const size_t off = (size_t)row * K + k0 + ((pos ^ (row & 7)) * 8);
      gl_lds16(A + (size_t)rowA0 * K + off, As + c * 8);
      gl_lds16(B + (size_t)rowB0 * K + off, Bs + c * 8);
    }
    __syncthreads();
#pragma unroll
    for (int kk2 = 0; kk2 < 2; kk2++) {
      bf16x8 af[4], bg[4];
#pragma unroll
      for (int i = 0; i < 4; i++) {
        const int rr = wm + i * 16 + l16;  // rr&7 == l16&7
        const int ci = (kk2 * 4 + quad) ^ (l16 & 7);
        af[i] = *(const bf16x8*)(As + rr * 64 + ci * 8);
      }
#pragma unroll
      for (int j = 0; j < 4; j++) {
        const int rr = wn + j * 16 + l16;
        const int ci = (kk2 * 4 + quad) ^ (l16 & 7);
        bg[j] = *(const bf16x8*)(Bs + rr * 64 + ci * 8);
      }
#pragma unroll
      for (int i = 0; i < 4; i++)
#pragma unroll
        for (int j = 0; j < 4; j++)
          acc[i][j] = MFMA16(af[i], bg[j], acc[i][j], 0, 0, 0);
    }
  }
}

// ---------------------------------------------------------------------------
// Kernel 1: qkv = x @ Wqkv^T ; scatter Q*0.125 (pre-scaled), K, Vt.
// Grid dim3(32,24): default order is XCD-optimal (XCD = bm%8 keeps its 4
// A-panels L2-resident; R13's chunked swizzle broke this, +6us).
// ---------------------------------------------------------------------------
__global__ __launch_bounds__(256, 3) void qkv_gemm(
    const bf16* __restrict__ x, const bf16* __restrict__ Wqkv,
    bf16* __restrict__ Qb, bf16* __restrict__ Kb, bf16* __restrict__ Vt) {
  __shared__ bf16 As[128 * 64];
  __shared__ bf16 Bs[128 * 64];
  f32x4 acc[4][4];
#pragma unroll
  for (int i = 0; i < 4; i++)
#pragma unroll
    for (int j = 0; j < 4; j++) acc[i][j] = (f32x4){0.f, 0.f, 0.f, 0.f};
  const int bm = blockIdx.x, bn = blockIdx.y;
  gemm_bt_acc<1024>(x, Wqkv, bm * 128, bn * 128, As, Bs, acc);

  const int t = threadIdx.x, w = t >> 6, l = t & 63;
  const int quad = l >> 4, l16 = l & 15;
  const int wm = (w >> 1) * 64, wn = (w & 1) * 64;
#pragma unroll
  for (int i = 0; i < 4; i++) {
    const int m0 = bm * 128 + wm + i * 16 + quad * 4;  // 4 contiguous m (=s)
    const int b = m0 >> 11, s0 = m0 & 2047;            // same b for all 4 r
#pragma unroll
    for (int j = 0; j < 4; j++) {
      const int n = bn * 128 + wn + j * 16 + l16;  // 0..3071
      const int which = n >> 10;
      const int nn = n & 1023;
      const int h = nn >> 6, d = nn & 63;
      const int bh = b * 16 + h;
      if (which == 2) {  // V: contiguous s -> one vectorized store
        bf16x4 v4;
#pragma unroll
        for (int r = 0; r < 4; r++)
          v4[r] = (short)__builtin_bit_cast(unsigned short,
                                            __float2bfloat16(acc[i][j][r]));
        *(bf16x4*)(Vt + ((size_t)bh * 64 + d) * 2048 + s0) = v4;
      } else {
        const float sc = (which == 0) ? 0.125f : 1.0f;  // fold softmax scale
        bf16* dst = (which == 0) ? Qb : Kb;
#pragma unroll
        for (int r = 0; r < 4; r++)
          dst[((size_t)bh * 2048 + s0 + r) * 64 + d] =
              __float2bfloat16(acc[i][j][r] * sc);
      }
    }
  }
}

// ---------------------------------------------------------------------------
// Kernel 2: causal flash attention — R6-EXACT (session best: attn 42.0us).
// ONE 64-row q-tile per block, grid 1024 (32 bh x 32 qt), 4 blocks/CU
// resident, Q in registers, LDS 32K, 2-barrier loop, snake qt order,
// __expf + perm-pack. Closed axes (all counter-verified regressions):
// dbuf/vmcnt (R1,R8), merge (R3), QBLK32 (R6), no-LDS (R7), KVBLK256 (R9),
// exp2/cvt_pk diet (R10-12: scratch-spill pathology), split-K (R15).
// ---------------------------------------------------------------------------
__global__ __launch_bounds__(256, 4) void attn_kernel(
    const bf16* __restrict__ Qb, const bf16* __restrict__ Kb,
    const bf16* __restrict__ Vt, bf16* __restrict__ attn) {
  __shared__ bf16 Ks[128 * 64];   // [krow][d]  swizzled (8 chunks/row)
  __shared__ bf16 Vts[64 * 128];  // [d][s]     swizzled (16 chunks/row)
  const int x = blockIdx.x;
  const int bh = x & 31;
  const int T = x >> 5;  // 0..31
  const int s = T >> 3, r = T & 7;
  const int qt = s * 8 + ((s & 1) ? 7 - r : r);  // balanced resident sets
  const int q0 = qt * 64;
  const int t = threadIdx.x, w = t >> 6, l = t & 63;
  const int quad = l >> 4, l16 = l & 15;
  const bf16x4 ones = {16256, 16256, 16256, 16256};  // bf16 1.0 x4
  const int b = bh >> 4, h = bh & 15;

  // ---- Q into registers: lane holds Q[q=qrow][d=kk*32+quad*8+e] ----
  const int qrow = q0 + w * 16 + l16;
  const bf16* Qg = Qb + ((size_t)bh * 2048 + qrow) * 64 + quad * 8;
  bf16x8 qreg[2];
  qreg[0] = *(const bf16x8*)(Qg);
  qreg[1] = *(const bf16x8*)(Qg + 32);

  f32x4 oacc[4];  // [md d-16]; O^T: q=l16, d=quad*4+reg
  f32x4 lacc = (f32x4){0.f, 0.f, 0.f, 0.f};  // ones·P = denominator
#pragma unroll
  for (int md = 0; md < 4; md++) oacc[md] = (f32x4){0.f, 0.f, 0.f, 0.f};

  const int njj = (qt + 2) >> 1;  // 128-wide tiles covering cols 0..q0+63
  for (int jj = 0; jj < njj; jj++) {
    const int j0 = jj * 128;
    __syncthreads();  // prior iter's Ks/Vts reads complete
    const bf16* Kg = Kb + ((size_t)bh * 2048 + j0) * 64;
#pragma unroll
    for (int c = t; c < 1024; c += 256) {
      const int row = c >> 3, pos = c & 7;
      gl_lds16(Kg + (row * 8 + (pos ^ (row & 7))) * 8, Ks + c * 8);
    }
    const bf16* Vg = Vt + (size_t)bh * 64 * 2048 + j0;
#pragma unroll
    for (int c = t; c < 1024; c += 256) {
      const int d = c >> 4, pos = c & 15;
      gl_lds16(Vg + (size_t)d * 2048 + ((pos ^ (d & 15)) * 8), Vts + c * 8);
    }
    __syncthreads();  // staging visible

    // ---- S^T = K Q^T : A=K[s][d] (M=128), B=Q^T[d][q] (N=16 of wave) ----
    f32x4 sacc[8];  // [mt s-16];  C-layout: q=l16, s=quad*4+reg
#pragma unroll
    for (int mt = 0; mt < 8; mt++) sacc[mt] = (f32x4){0.f, 0.f, 0.f, 0.f};
#pragma unroll
    for (int kk = 0; kk < 2; kk++) {
#pragma unroll
      for (int mt = 0; mt < 8; mt++) {
        const int row = mt * 16 + l16;
        const int pos = (kk * 4 + quad) ^ (l16 & 7);  // row&7 == l16&7
        bf16x8 kf = *(const bf16x8*)(Ks + row * 64 + pos * 8);
        sacc[mt] = MFMA16(kf, qreg[kk], sacc[mt], 0, 0, 0);
      }
    }

    // ---- P^T = exp(S^T) packed via v_perm (B-frag layout) ----
    bf16x4 pfrag[8];      // [kt = s-16-block]
    if (jj == njj - 1) {  // wave-uniform: only the last tile masks
#pragma unroll
      for (int mt = 0; mt < 8; mt++) {
        unsigned rb[4];
#pragma unroll
        for (int r2 = 0; r2 < 4; r2++) {
          const int sg = j0 + mt * 16 + quad * 4 + r2;
          const float p = (sg <= qrow) ? __expf(sacc[mt][r2]) : 0.f;
          rb[r2] = __builtin_bit_cast(unsigned, p) + 0x8000u;
        }
        i32x2 pk;
        pk.x = (int)__builtin_amdgcn_perm(rb[1], rb[0], 0x07060302u);
        pk.y = (int)__builtin_amdgcn_perm(rb[3], rb[2], 0x07060302u);
        pfrag[mt] = __builtin_bit_cast(bf16x4, pk);
      }
    } else {
#pragma unroll
      for (int mt = 0; mt < 8; mt++) {
        unsigned rb[4];
#pragma unroll
        for (int r2 = 0; r2 < 4; r2++) {
          const float p = __expf(sacc[mt][r2]);
          rb[r2] = __builtin_bit_cast(unsigned, p) + 0x8000u;
        }
        i32x2 pk;
        pk.x = (int)__builtin_amdgcn_perm(rb[1], rb[0], 0x07060302u);
        pk.y = (int)__builtin_amdgcn_perm(rb[3], rb[2], 0x07060302u);
        pfrag[mt] = __builtin_bit_cast(bf16x4, pk);
      }
    }

    // ---- O^T += V^T P^T ; lacc += ones·P^T (denominator in MFMA pipe) ----
#pragma unroll
    for (int kt = 0; kt < 8; kt++) {
      lacc = MFMA16K16(ones, pfrag[kt], lacc, 0, 0, 0);
#pragma unroll
      for (int md = 0; md < 4; md++) {
        const int d = md * 16 + l16;
        const int pos = (kt * 2 + (quad >> 1)) ^ l16;  // d&15 == l16
        bf16x4 va = *(const bf16x4*)(Vts + d * 128 + pos * 8 + (quad & 1) * 4);
        oacc[md] = MFMA16K16(va, pfrag[kt], oacc[md], 0, 0, 0);
      }
    }
  }

  // ---- epilogue: every lane holds its q's full denominator ----
  const float inv = 1.0f / lacc[0];
#pragma unroll
  for (int md = 0; md < 4; md++) {
    bf16x4 o4;
#pragma unroll
    for (int r2 = 0; r2 < 4; r2++) o4[r2] = f2bf(oacc[md][r2] * inv);
    *(bf16x4*)(attn + ((size_t)b * 2048 + qrow) * 1024 + h * 64 + md * 16 +
               quad * 4) = o4;
  }
}

// ---------------------------------------------------------------------------
// Kernel 3: out = attn @ Wout^T (fp32 output). 128x64 tiles -> grid (32,16)
// (default order is XCD-optimal: XCD=bm%8 keeps A-panels L2-resident).
// ---------------------------------------------------------------------------
__global__ __launch_bounds__(256) void out_gemm(
    const bf16* __restrict__ attn, const bf16* __restrict__ Wout,
    float* __restrict__ out) {
  __shared__ bf16 As[128 * 32];
  __shared__ bf16 Bs[64 * 32];
  f32x4 acc[4][2];
#pragma unroll
  for (int i = 0; i < 4; i++)
#pragma unroll
    for (int j = 0; j < 2; j++) acc[i][j] = (f32x4){0.f, 0.f, 0.f, 0.f};
  const int bm = blockIdx.x, bn = blockIdx.y;
  const int t = threadIdx.x, w = t >> 6, l = t & 63;
  const int quad = l >> 4, l16 = l & 15;
  const int wm = (w >> 1) * 64, wn = (w & 1) * 32;
  const int c0 = t, c1 = t + 256;
  const bf16* a0 = attn + (size_t)(bm * 128 + (c0 >> 2)) * 1024 + (c0 & 3) * 8;
  const bf16* a1 = attn + (size_t)(bm * 128 + (c1 >> 2)) * 1024 + (c1 & 3) * 8;
  const bf16* b0 = Wout + (size_t)(bn * 64 + (t >> 2)) * 1024 + (t & 3) * 8;
  for (int k0 = 0; k0 < 1024; k0 += 32) {
    __syncthreads();
    gl_lds16(a0 + k0, As + c0 * 8);
    gl_lds16(a1 + k0, As + c1 * 8);
    gl_lds16(b0 + k0, Bs + t * 8);
    __syncthreads();
    bf16x8 af[4], bg[2];
#pragma unroll
    for (int i = 0; i < 4; i++)
      af[i] = *(const bf16x8*)(As + (wm + i * 16 + l16) * 32 + quad * 8);
#pragma unroll
    for (int j = 0; j < 2; j++)
      bg[j] = *(const bf16x8*)(Bs + (wn + j * 16 + l16) * 32 + quad * 8);
#pragma unroll
    for (int i = 0; i < 4; i++)
#pragma unroll
      for (int j = 0; j < 2; j++)
        acc[i][j] = MFMA16(af[i], bg[j], acc[i][j], 0, 0, 0);
  }
#pragma unroll
  for (int i = 0; i < 4; i++) {
#pragma unroll
    for (int j = 0; j < 2; j++) {
      const int n = bn * 64 + wn + j * 16 + l16;
#pragma unroll
      for (int r = 0; r < 4; r++) {
        const int m = bm * 128 + wm + i * 16 + quad * 4 + r;
        out[(size_t)m * 1024 + n] = acc[i][j][r];
      }
    }
  }
}

// ---------------------------------------------------------------------------
extern "C" void kernel_launch(void* const* d_in, const int* in_sizes, int n_in,
                              void* d_out, int out_size, void* d_ws, size_t ws_size,
                              hipStream_t stream) {
  const float* x = (const float*)d_in[0];      // [2,2048,1024] fp32
  const float* Wqkv = (const float*)d_in[1];   // [3072,1024]   fp32
  const float* Wout = (const float*)d_in[2];   // [1024,1024]   fp32
  float* out = (float*)d_out;                  // [2,2048,1024] fp32

  char* ws = (char*)d_ws;
  const size_t MB = 1024 * 1024;
  bf16* xb = (bf16*)(ws + 0 * MB);      // [4096][1024]  8 MB (consumed by qkv)
  bf16* at = (bf16*)(ws + 0 * MB);      // [4096][1024]  8 MB (alias, after qkv)
  bf16* Wqkvb = (bf16*)(ws + 8 * MB);   // [3072][1024]  6 MB
  bf16* Woutb = (bf16*)(ws + 14 * MB);  // [1024][1024]  2 MB
  bf16* Qb = (bf16*)(ws + 16 * MB);     // [32][2048][64] 8 MB (pre-scaled)
  bf16* Kb = (bf16*)(ws + 24 * MB);     // [32][2048][64] 8 MB
  bf16* Vt = (bf16*)(ws + 32 * MB);     // [32][64][2048] 8 MB

  cvt_all<<<8192, 256, 0, stream>>>(x, Wqkv, Wout, xb, Wqkvb, Woutb);
  qkv_gemm<<<dim3(32, 24), 256, 0, stream>>>(xb, Wqkvb, Qb, Kb, Vt);
  attn_kernel<<<1024, 256, 0, stream>>>(Qb, Kb, Vt, at);
  out_gemm<<<dim3(32, 16), 256, 0, stream>>>(at, Woutb, out);
}

// Round 17
// 159.092 us; speedup vs baseline: 1.0823x; 1.0283x over previous
//
#include <hip/hip_runtime.h>
#include <hip/hip_bf16.h>
#include <math.h>

using bf16 = __hip_bfloat16;
typedef __attribute__((ext_vector_type(8))) short bf16x8;
typedef __attribute__((ext_vector_type(4))) short bf16x4;
typedef __attribute__((ext_vector_type(4))) float f32x4;
typedef __attribute__((ext_vector_type(2))) int i32x2;

// async global->LDS, 16B per lane (guide §5: width=16 is the m93->m97 2x step)
static __device__ __forceinline__ void gl_lds16(const void* g, void* l) {
  __builtin_amdgcn_global_load_lds(
      (const __attribute__((address_space(1))) unsigned int*)g,
      (__attribute__((address_space(3))) unsigned int*)l, 16, 0, 0);
}

#define MFMA16 __builtin_amdgcn_mfma_f32_16x16x32_bf16
#define MFMA16K16 __builtin_amdgcn_mfma_f32_16x16x16bf16_1k

// fast f32->bf16 (round-to-nearest-ish; fine for p in [0,1] and O outputs)
static __device__ __forceinline__ short f2bf(float f) {
  return (short)((__builtin_bit_cast(unsigned int, f) + 0x8000u) >> 16);
}

// ---------------------------------------------------------------------------
// Kernel 0: fp32 -> bf16 for all three inputs in ONE launch.
// R17: 8 floats/thread, 16B stores (were 8B — half-width for a BW-bound op,
// G13). grid 4096: [0,2048) x, [2048,3584) Wqkv, [3584,4096) Wout.
// ---------------------------------------------------------------------------
__global__ __launch_bounds__(256) void cvt_all(
    const float* __restrict__ x, const float* __restrict__ wqkv,
    const float* __restrict__ wout, bf16* __restrict__ xb,
    bf16* __restrict__ wqkvb, bf16* __restrict__ woutb) {
  const int blk = blockIdx.x;
  const float* src;
  bf16* dst;
  int base;
  if (blk < 2048) {
    src = x; dst = xb; base = blk;
  } else if (blk < 3584) {
    src = wqkv; dst = wqkvb; base = blk - 2048;
  } else {
    src = wout; dst = woutb; base = blk - 3584;
  }
  const int i = (base * 256 + threadIdx.x) * 8;
  const float4 v0 = *(const float4*)(src + i);
  const float4 v1 = *(const float4*)(src + i + 4);
  bf16x8 o;
  o[0] = f2bf(v0.x);
  o[1] = f2bf(v0.y);
  o[2] = f2bf(v0.z);
  o[3] = f2bf(v0.w);
  o[4] = f2bf(v1.x);
  o[5] = f2bf(v1.y);
  o[6] = f2bf(v1.z);
  o[7] = f2bf(v1.w);
  *(bf16x8*)(dst + i) = o;
}

// ---------------------------------------------------------------------------
// 128x128 block of C[m,n] = sum_k A[m,k]*B[n,k]   (A:[*,K] row-major, B:[*,K])
// R14: BK=64, XOR-swizzled LDS (pos^(row&7)) on both stage-source and read.
// ---------------------------------------------------------------------------
template <int K>
static __device__ __forceinline__ void gemm_bt_acc(
    const bf16* __restrict__ A, const bf16* __restrict__ B,
    int rowA0, int rowB0, bf16* As, bf16* Bs, f32x4 acc[4][4]) {
  const int t = threadIdx.x;
  const int w = t >> 6, l = t & 63;
  const int quad = l >> 4, l16 = l & 15;
  const int wm = (w >> 1) * 64, wn = (w & 1) * 64;
  for (int k0 = 0; k0 < K; k0 += 64) {
    __syncthreads();
#pragma unroll
    for (int ii = 0; ii < 4; ii++) {
      const int c = t + ii * 256;  // 0..1023: row = c>>3 (128B rows), pos 0..7
      const int row = c >> 3, pos = c & 7;
      const size_t off = (size_t)row * K + k0 + ((pos ^ (row & 7)) * 8);
      gl_lds16(A + (size_t)rowA0 * K + off, As + c * 8);
      gl_lds16(B + (size_t)rowB0 * K + off, Bs + c * 8);
    }
    __syncthreads();
#pragma unroll
    for (int kk2 = 0; kk2 < 2; kk2++) {
      bf16x8 af[4], bg[4];
#pragma unroll
      for (int i = 0; i < 4; i++) {
        const int rr = wm + i * 16 + l16;  // rr&7 == l16&7
        const int ci = (kk2 * 4 + quad) ^ (l16 & 7);
        af[i] = *(const bf16x8*)(As + rr * 64 + ci * 8);
      }
#pragma unroll
      for (int j = 0; j < 4; j++) {
        const int rr = wn + j * 16 + l16;
        const int ci = (kk2 * 4 + quad) ^ (l16 & 7);
        bg[j] = *(const bf16x8*)(Bs + rr * 64 + ci * 8);
      }
#pragma unroll
      for (int i = 0; i < 4; i++)
#pragma unroll
        for (int j = 0; j < 4; j++)
          acc[i][j] = MFMA16(af[i], bg[j], acc[i][j], 0, 0, 0);
    }
  }
}

// ---------------------------------------------------------------------------
// Kernel 1: qkv = x @ Wqkv^T ; scatter Q*0.125 (pre-scaled), K, Vt.
// Grid dim3(32,24): default order is XCD-optimal (XCD = bm%8 keeps its 4
// A-panels L2-resident; R13's chunked swizzle broke this, +6us).
// ---------------------------------------------------------------------------
__global__ __launch_bounds__(256, 3) void qkv_gemm(
    const bf16* __restrict__ x, const bf16* __restrict__ Wqkv,
    bf16* __restrict__ Qb, bf16* __restrict__ Kb, bf16* __restrict__ Vt) {
  __shared__ bf16 As[128 * 64];
  __shared__ bf16 Bs[128 * 64];
  f32x4 acc[4][4];
#pragma unroll
  for (int i = 0; i < 4; i++)
#pragma unroll
    for (int j = 0; j < 4; j++) acc[i][j] = (f32x4){0.f, 0.f, 0.f, 0.f};
  const int bm = blockIdx.x, bn = blockIdx.y;
  gemm_bt_acc<1024>(x, Wqkv, bm * 128, bn * 128, As, Bs, acc);

  const int t = threadIdx.x, w = t >> 6, l = t & 63;
  const int quad = l >> 4, l16 = l & 15;
  const int wm = (w >> 1) * 64, wn = (w & 1) * 64;
#pragma unroll
  for (int i = 0; i < 4; i++) {
    const int m0 = bm * 128 + wm + i * 16 + quad * 4;  // 4 contiguous m (=s)
    const int b = m0 >> 11, s0 = m0 & 2047;            // same b for all 4 r
#pragma unroll
    for (int j = 0; j < 4; j++) {
      const int n = bn * 128 + wn + j * 16 + l16;  // 0..3071
      const int which = n >> 10;
      const int nn = n & 1023;
      const int h = nn >> 6, d = nn & 63;
      const int bh = b * 16 + h;
      if (which == 2) {  // V: contiguous s -> one vectorized store
        bf16x4 v4;
#pragma unroll
        for (int r = 0; r < 4; r++)
          v4[r] = (short)__builtin_bit_cast(unsigned short,
                                            __float2bfloat16(acc[i][j][r]));
        *(bf16x4*)(Vt + ((size_t)bh * 64 + d) * 2048 + s0) = v4;
      } else {
        const float sc = (which == 0) ? 0.125f : 1.0f;  // fold softmax scale
        bf16* dst = (which == 0) ? Qb : Kb;
#pragma unroll
        for (int r = 0; r < 4; r++)
          dst[((size_t)bh * 2048 + s0 + r) * 64 + d] =
              __float2bfloat16(acc[i][j][r] * sc);
      }
    }
  }
}

// ---------------------------------------------------------------------------
// Kernel 2: causal flash attention — R6-EXACT (session best: attn 42.0us).
// ONE 64-row q-tile per block, grid 1024 (32 bh x 32 qt), 4 blocks/CU
// resident, Q in registers, LDS 32K, 2-barrier loop, snake qt order,
// __expf + perm-pack. Closed axes (all counter-verified regressions):
// dbuf/vmcnt (R1,R8), merge (R3), QBLK32 (R6), no-LDS (R7), KVBLK256 (R9),
// exp2/cvt_pk diet (R10-12: scratch-spill pathology), split-K (R15).
// ---------------------------------------------------------------------------
__global__ __launch_bounds__(256, 4) void attn_kernel(
    const bf16* __restrict__ Qb, const bf16* __restrict__ Kb,
    const bf16* __restrict__ Vt, bf16* __restrict__ attn) {
  __shared__ bf16 Ks[128 * 64];   // [krow][d]  swizzled (8 chunks/row)
  __shared__ bf16 Vts[64 * 128];  // [d][s]     swizzled (16 chunks/row)
  const int x = blockIdx.x;
  const int bh = x & 31;
  const int T = x >> 5;  // 0..31
  const int s = T >> 3, r = T & 7;
  const int qt = s * 8 + ((s & 1) ? 7 - r : r);  // balanced resident sets
  const int q0 = qt * 64;
  const int t = threadIdx.x, w = t >> 6, l = t & 63;
  const int quad = l >> 4, l16 = l & 15;
  const bf16x4 ones = {16256, 16256, 16256, 16256};  // bf16 1.0 x4
  const int b = bh >> 4, h = bh & 15;

  // ---- Q into registers: lane holds Q[q=qrow][d=kk*32+quad*8+e] ----
  const int qrow = q0 + w * 16 + l16;
  const bf16* Qg = Qb + ((size_t)bh * 2048 + qrow) * 64 + quad * 8;
  bf16x8 qreg[2];
  qreg[0] = *(const bf16x8*)(Qg);
  qreg[1] = *(const bf16x8*)(Qg + 32);

  f32x4 oacc[4];  // [md d-16]; O^T: q=l16, d=quad*4+reg
  f32x4 lacc = (f32x4){0.f, 0.f, 0.f, 0.f};  // ones·P = denominator
#pragma unroll
  for (int md = 0; md < 4; md++) oacc[md] = (f32x4){0.f, 0.f, 0.f, 0.f};

  const int njj = (qt + 2) >> 1;  // 128-wide tiles covering cols 0..q0+63
  for (int jj = 0; jj < njj; jj++) {
    const int j0 = jj * 128;
    __syncthreads();  // prior iter's Ks/Vts reads complete
    const bf16* Kg = Kb + ((size_t)bh * 2048 + j0) * 64;
#pragma unroll
    for (int c = t; c < 1024; c += 256) {
      const int row = c >> 3, pos = c & 7;
      gl_lds16(Kg + (row * 8 + (pos ^ (row & 7))) * 8, Ks + c * 8);
    }
    const bf16* Vg = Vt + (size_t)bh * 64 * 2048 + j0;
#pragma unroll
    for (int c = t; c < 1024; c += 256) {
      const int d = c >> 4, pos = c & 15;
      gl_lds16(Vg + (size_t)d * 2048 + ((pos ^ (d & 15)) * 8), Vts + c * 8);
    }
    __syncthreads();  // staging visible

    // ---- S^T = K Q^T : A=K[s][d] (M=128), B=Q^T[d][q] (N=16 of wave) ----
    f32x4 sacc[8];  // [mt s-16];  C-layout: q=l16, s=quad*4+reg
#pragma unroll
    for (int mt = 0; mt < 8; mt++) sacc[mt] = (f32x4){0.f, 0.f, 0.f, 0.f};
#pragma unroll
    for (int kk = 0; kk < 2; kk++) {
#pragma unroll
      for (int mt = 0; mt < 8; mt++) {
        const int row = mt * 16 + l16;
        const int pos = (kk * 4 + quad) ^ (l16 & 7);  // row&7 == l16&7
        bf16x8 kf = *(const bf16x8*)(Ks + row * 64 + pos * 8);
        sacc[mt] = MFMA16(kf, qreg[kk], sacc[mt], 0, 0, 0);
      }
    }

    // ---- P^T = exp(S^T) packed via v_perm (B-frag layout) ----
    bf16x4 pfrag[8];      // [kt = s-16-block]
    if (jj == njj - 1) {  // wave-uniform: only the last tile masks
#pragma unroll
      for (int mt = 0; mt < 8; mt++) {
        unsigned rb[4];
#pragma unroll
        for (int r2 = 0; r2 < 4; r2++) {
          const int sg = j0 + mt * 16 + quad * 4 + r2;
          const float p = (sg <= qrow) ? __expf(sacc[mt][r2]) : 0.f;
          rb[r2] = __builtin_bit_cast(unsigned, p) + 0x8000u;
        }
        i32x2 pk;
        pk.x = (int)__builtin_amdgcn_perm(rb[1], rb[0], 0x07060302u);
        pk.y = (int)__builtin_amdgcn_perm(rb[3], rb[2], 0x07060302u);
        pfrag[mt] = __builtin_bit_cast(bf16x4, pk);
      }
    } else {
#pragma unroll
      for (int mt = 0; mt < 8; mt++) {
        unsigned rb[4];
#pragma unroll
        for (int r2 = 0; r2 < 4; r2++) {
          const float p = __expf(sacc[mt][r2]);
          rb[r2] = __builtin_bit_cast(unsigned, p) + 0x8000u;
        }
        i32x2 pk;
        pk.x = (int)__builtin_amdgcn_perm(rb[1], rb[0], 0x07060302u);
        pk.y = (int)__builtin_amdgcn_perm(rb[3], rb[2], 0x07060302u);
        pfrag[mt] = __builtin_bit_cast(bf16x4, pk);
      }
    }

    // ---- O^T += V^T P^T ; lacc += ones·P^T (denominator in MFMA pipe) ----
#pragma unroll
    for (int kt = 0; kt < 8; kt++) {
      lacc = MFMA16K16(ones, pfrag[kt], lacc, 0, 0, 0);
#pragma unroll
      for (int md = 0; md < 4; md++) {
        const int d = md * 16 + l16;
        const int pos = (kt * 2 + (quad >> 1)) ^ l16;  // d&15 == l16
        bf16x4 va = *(const bf16x4*)(Vts + d * 128 + pos * 8 + (quad & 1) * 4);
        oacc[md] = MFMA16K16(va, pfrag[kt], oacc[md], 0, 0, 0);
      }
    }
  }

  // ---- epilogue: every lane holds its q's full denominator ----
  const float inv = 1.0f / lacc[0];
#pragma unroll
  for (int md = 0; md < 4; md++) {
    bf16x4 o4;
#pragma unroll
    for (int r2 = 0; r2 < 4; r2++) o4[r2] = f2bf(oacc[md][r2] * inv);
    *(bf16x4*)(attn + ((size_t)b * 2048 + qrow) * 1024 + h * 64 + md * 16 +
               quad * 4) = o4;
  }
}

// ---------------------------------------------------------------------------
// Kernel 3: out = attn @ Wout^T (fp32 output). 128x64 tiles -> grid (32,16).
// R17: BK=64 with the R14-verified swizzled staging/read (same involution
// algebra as qkv; B-tile is 64 rows). LDS 24KB. 16 K-iterations (was 32).
// ---------------------------------------------------------------------------
__global__ __launch_bounds__(256) void out_gemm(
    const bf16* __restrict__ attn, const bf16* __restrict__ Wout,
    float* __restrict__ out) {
  __shared__ bf16 As[128 * 64];
  __shared__ bf16 Bs[64 * 64];
  f32x4 acc[4][2];
#pragma unroll
  for (int i = 0; i < 4; i++)
#pragma unroll
    for (int j = 0; j < 2; j++) acc[i][j] = (f32x4){0.f, 0.f, 0.f, 0.f};
  const int bm = blockIdx.x, bn = blockIdx.y;
  const int t = threadIdx.x, w = t >> 6, l = t & 63;
  const int quad = l >> 4, l16 = l & 15;
  const int wm = (w >> 1) * 64, wn = (w & 1) * 32;
  for (int k0 = 0; k0 < 1024; k0 += 64) {
    __syncthreads();
#pragma unroll
    for (int ii = 0; ii < 4; ii++) {  // A: 128 rows x 8 chunks = 1024
      const int c = t + ii * 256;
      const int row = c >> 3, pos = c & 7;
      gl_lds16(attn + (size_t)(bm * 128 + row) * 1024 + k0 +
                   ((pos ^ (row & 7)) * 8),
               As + c * 8);
    }
#pragma unroll
    for (int ii = 0; ii < 2; ii++) {  // B: 64 rows x 8 chunks = 512
      const int c = t + ii * 256;
      const int row = c >> 3, pos = c & 7;
      gl_lds16(Wout + (size_t)(bn * 64 + row) * 1024 + k0 +
                   ((pos ^ (row & 7)) * 8),
               Bs + c * 8);
    }
    __syncthreads();
#pragma unroll
    for (int kk2 = 0; kk2 < 2; kk2++) {
      bf16x8 af[4], bg[2];
#pragma unroll
      for (int i = 0; i < 4; i++) {
        const int rr = wm + i * 16 + l16;  // rr&7 == l16&7
        const int ci = (kk2 * 4 + quad) ^ (l16 & 7);
        af[i] = *(const bf16x8*)(As + rr * 64 + ci * 8);
      }
#pragma unroll
      for (int j = 0; j < 2; j++) {
        const int rr = wn + j * 16 + l16;
        const int ci = (kk2 * 4 + quad) ^ (l16 & 7);
        bg[j] = *(const bf16x8*)(Bs + rr * 64 + ci * 8);
      }
#pragma unroll
      for (int i = 0; i < 4; i++)
#pragma unroll
        for (int j = 0; j < 2; j++)
          acc[i][j] = MFMA16(af[i], bg[j], acc[i][j], 0, 0, 0);
    }
  }
#pragma unroll
  for (int i = 0; i < 4; i++) {
#pragma unroll
    for (int j = 0; j < 2; j++) {
      const int n = bn * 64 + wn + j * 16 + l16;
#pragma unroll
      for (int r = 0; r < 4; r++) {
        const int m = bm * 128 + wm + i * 16 + quad * 4 + r;
        out[(size_t)m * 1024 + n] = acc[i][j][r];
      }
    }
  }
}

// ---------------------------------------------------------------------------
extern "C" void kernel_launch(void* const* d_in, const int* in_sizes, int n_in,
                              void* d_out, int out_size, void* d_ws, size_t ws_size,
                              hipStream_t stream) {
  const float* x = (const float*)d_in[0];      // [2,2048,1024] fp32
  const float* Wqkv = (const float*)d_in[1];   // [3072,1024]   fp32
  const float* Wout = (const float*)d_in[2];   // [1024,1024]   fp32
  float* out = (float*)d_out;                  // [2,2048,1024] fp32

  char* ws = (char*)d_ws;
  const size_t MB = 1024 * 1024;
  bf16* xb = (bf16*)(ws + 0 * MB);      // [4096][1024]  8 MB (consumed by qkv)
  bf16* at = (bf16*)(ws + 0 * MB);      // [4096][1024]  8 MB (alias, after qkv)
  bf16* Wqkvb = (bf16*)(ws + 8 * MB);   // [3072][1024]  6 MB
  bf16* Woutb = (bf16*)(ws + 14 * MB);  // [1024][1024]  2 MB
  bf16* Qb = (bf16*)(ws + 16 * MB);     // [32][2048][64] 8 MB (pre-scaled)
  bf16* Kb = (bf16*)(ws + 24 * MB);     // [32][2048][64] 8 MB
  bf16* Vt = (bf16*)(ws + 32 * MB);     // [32][64][2048] 8 MB

  cvt_all<<<4096, 256, 0, stream>>>(x, Wqkv, Wout, xb, Wqkvb, Woutb);
  qkv_gemm<<<dim3(32, 24), 256, 0, stream>>>(xb, Wqkvb, Qb, Kb, Vt);
  attn_kernel<<<1024, 256, 0, stream>>>(Qb, Kb, Vt, at);
  out_gemm<<<dim3(32, 16), 256, 0, stream>>>(at, Woutb, out);
}

// Round 18
// 158.999 us; speedup vs baseline: 1.0829x; 1.0006x over previous
//
#include <hip/hip_runtime.h>
#include <hip/hip_bf16.h>
#include <math.h>

using bf16 = __hip_bfloat16;
typedef __attribute__((ext_vector_type(8))) short bf16x8;
typedef __attribute__((ext_vector_type(4))) short bf16x4;
typedef __attribute__((ext_vector_type(4))) float f32x4;
typedef __attribute__((ext_vector_type(2))) int i32x2;

// async global->LDS, 16B per lane (guide §5: width=16 is the m93->m97 2x step)
static __device__ __forceinline__ void gl_lds16(const void* g, void* l) {
  __builtin_amdgcn_global_load_lds(
      (const __attribute__((address_space(1))) unsigned int*)g,
      (__attribute__((address_space(3))) unsigned int*)l, 16, 0, 0);
}

#define MFMA16 __builtin_amdgcn_mfma_f32_16x16x32_bf16
#define MFMA16K16 __builtin_amdgcn_mfma_f32_16x16x16bf16_1k

// fast f32->bf16 (round-to-nearest-ish; fine for p in [0,1] and O outputs)
static __device__ __forceinline__ short f2bf(float f) {
  return (short)((__builtin_bit_cast(unsigned int, f) + 0x8000u) >> 16);
}

// ---------------------------------------------------------------------------
// Kernel 0: fp32 -> bf16 for all three inputs in ONE launch.
// R18: 16 floats/thread, 2x16B stores. grid 2048: [0,1024) x,
// [1024,1792) Wqkv, [1792,2048) Wout.
// ---------------------------------------------------------------------------
__global__ __launch_bounds__(256) void cvt_all(
    const float* __restrict__ x, const float* __restrict__ wqkv,
    const float* __restrict__ wout, bf16* __restrict__ xb,
    bf16* __restrict__ wqkvb, bf16* __restrict__ woutb) {
  const int blk = blockIdx.x;
  const float* src;
  bf16* dst;
  int base;
  if (blk < 1024) {
    src = x; dst = xb; base = blk;
  } else if (blk < 1792) {
    src = wqkv; dst = wqkvb; base = blk - 1024;
  } else {
    src = wout; dst = woutb; base = blk - 1792;
  }
  const int i = (base * 256 + threadIdx.x) * 16;
#pragma unroll
  for (int half = 0; half < 2; half++) {
    const float4 v0 = *(const float4*)(src + i + half * 8);
    const float4 v1 = *(const float4*)(src + i + half * 8 + 4);
    bf16x8 o;
    o[0] = f2bf(v0.x);
    o[1] = f2bf(v0.y);
    o[2] = f2bf(v0.z);
    o[3] = f2bf(v0.w);
    o[4] = f2bf(v1.x);
    o[5] = f2bf(v1.y);
    o[6] = f2bf(v1.z);
    o[7] = f2bf(v1.w);
    *(bf16x8*)(dst + i + half * 8) = o;
  }
}

// ---------------------------------------------------------------------------
// 128x128 block of C[m,n] = sum_k A[m,k]*B[n,k]   (A:[*,K] row-major, B:[*,K])
// R14: BK=64, XOR-swizzled LDS (pos^(row&7)) on both stage-source and read.
// ---------------------------------------------------------------------------
template <int K>
static __device__ __forceinline__ void gemm_bt_acc(
    const bf16* __restrict__ A, const bf16* __restrict__ B,
    int rowA0, int rowB0, bf16* As, bf16* Bs, f32x4 acc[4][4]) {
  const int t = threadIdx.x;
  const int w = t >> 6, l = t & 63;
  const int quad = l >> 4, l16 = l & 15;
  const int wm = (w >> 1) * 64, wn = (w & 1) * 64;
  for (int k0 = 0; k0 < K; k0 += 64) {
    __syncthreads();
#pragma unroll
    for (int ii = 0; ii < 4; ii++) {
      const int c = t + ii * 256;  // 0..1023: row = c>>3 (128B rows), pos 0..7
      const int row = c >> 3, pos = c & 7;
      const size_t off = (size_t)row * K + k0 + ((pos ^ (row & 7)) * 8);
      gl_lds16(A + (size_t)rowA0 * K + off, As + c * 8);
      gl_lds16(B + (size_t)rowB0 * K + off, Bs + c * 8);
    }
    __syncthreads();
#pragma unroll
    for (int kk2 = 0; kk2 < 2; kk2++) {
      bf16x8 af[4], bg[4];
#pragma unroll
      for (int i = 0; i < 4; i++) {
        const int rr = wm + i * 16 + l16;  // rr&7 == l16&7
        const int ci = (kk2 * 4 + quad) ^ (l16 & 7);
        af[i] = *(const bf16x8*)(As + rr * 64 + ci * 8);
      }
#pragma unroll
      for (int j = 0; j < 4; j++) {
        const int rr = wn + j * 16 + l16;
        const int ci = (kk2 * 4 + quad) ^ (l16 & 7);
        bg[j] = *(const bf16x8*)(Bs + rr * 64 + ci * 8);
      }
#pragma unroll
      for (int i = 0; i < 4; i++)
#pragma unroll
        for (int j = 0; j < 4; j++)
          acc[i][j] = MFMA16(af[i], bg[j], acc[i][j], 0, 0, 0);
    }
  }
}

// ---------------------------------------------------------------------------
// Kernel 1: qkv = x @ Wqkv^T ; scatter Q*0.125 (pre-scaled), K, Vt.
// Grid dim3(32,24): default order is XCD-optimal (XCD = bm%8 keeps its 4
// A-panels L2-resident; R13's chunked swizzle broke this, +6us).
// BK stays 64: BK=128 would need 64KB LDS -> 3->2 blocks/CU (m132 regression).
// ---------------------------------------------------------------------------
__global__ __launch_bounds__(256, 3) void qkv_gemm(
    const bf16* __restrict__ x, const bf16* __restrict__ Wqkv,
    bf16* __restrict__ Qb, bf16* __restrict__ Kb, bf16* __restrict__ Vt) {
  __shared__ bf16 As[128 * 64];
  __shared__ bf16 Bs[128 * 64];
  f32x4 acc[4][4];
#pragma unroll
  for (int i = 0; i < 4; i++)
#pragma unroll
    for (int j = 0; j < 4; j++) acc[i][j] = (f32x4){0.f, 0.f, 0.f, 0.f};
  const int bm = blockIdx.x, bn = blockIdx.y;
  gemm_bt_acc<1024>(x, Wqkv, bm * 128, bn * 128, As, Bs, acc);

  const int t = threadIdx.x, w = t >> 6, l = t & 63;
  const int quad = l >> 4, l16 = l & 15;
  const int wm = (w >> 1) * 64, wn = (w & 1) * 64;
#pragma unroll
  for (int i = 0; i < 4; i++) {
    const int m0 = bm * 128 + wm + i * 16 + quad * 4;  // 4 contiguous m (=s)
    const int b = m0 >> 11, s0 = m0 & 2047;            // same b for all 4 r
#pragma unroll
    for (int j = 0; j < 4; j++) {
      const int n = bn * 128 + wn + j * 16 + l16;  // 0..3071
      const int which = n >> 10;
      const int nn = n & 1023;
      const int h = nn >> 6, d = nn & 63;
      const int bh = b * 16 + h;
      if (which == 2) {  // V: contiguous s -> one vectorized store
        bf16x4 v4;
#pragma unroll
        for (int r = 0; r < 4; r++)
          v4[r] = (short)__builtin_bit_cast(unsigned short,
                                            __float2bfloat16(acc[i][j][r]));
        *(bf16x4*)(Vt + ((size_t)bh * 64 + d) * 2048 + s0) = v4;
      } else {
        const float sc = (which == 0) ? 0.125f : 1.0f;  // fold softmax scale
        bf16* dst = (which == 0) ? Qb : Kb;
#pragma unroll
        for (int r = 0; r < 4; r++)
          dst[((size_t)bh * 2048 + s0 + r) * 64 + d] =
              __float2bfloat16(acc[i][j][r] * sc);
      }
    }
  }
}

// ---------------------------------------------------------------------------
// Kernel 2: causal flash attention — R6-EXACT (session best: attn 42.0us).
// ONE 64-row q-tile per block, grid 1024 (32 bh x 32 qt), 4 blocks/CU
// resident, Q in registers, LDS 32K, 2-barrier loop, snake qt order,
// __expf + perm-pack. Closed axes (all counter-verified regressions):
// dbuf/vmcnt (R1,R8), merge (R3), QBLK32 (R6), no-LDS (R7), KVBLK256 (R9),
// exp2/cvt_pk diet (R10-12: scratch-spill pathology), split-K (R15).
// ---------------------------------------------------------------------------
__global__ __launch_bounds__(256, 4) void attn_kernel(
    const bf16* __restrict__ Qb, const bf16* __restrict__ Kb,
    const bf16* __restrict__ Vt, bf16* __restrict__ attn) {
  __shared__ bf16 Ks[128 * 64];   // [krow][d]  swizzled (8 chunks/row)
  __shared__ bf16 Vts[64 * 128];  // [d][s]     swizzled (16 chunks/row)
  const int x = blockIdx.x;
  const int bh = x & 31;
  const int T = x >> 5;  // 0..31
  const int s = T >> 3, r = T & 7;
  const int qt = s * 8 + ((s & 1) ? 7 - r : r);  // balanced resident sets
  const int q0 = qt * 64;
  const int t = threadIdx.x, w = t >> 6, l = t & 63;
  const int quad = l >> 4, l16 = l & 15;
  const bf16x4 ones = {16256, 16256, 16256, 16256};  // bf16 1.0 x4
  const int b = bh >> 4, h = bh & 15;

  // ---- Q into registers: lane holds Q[q=qrow][d=kk*32+quad*8+e] ----
  const int qrow = q0 + w * 16 + l16;
  const bf16* Qg = Qb + ((size_t)bh * 2048 + qrow) * 64 + quad * 8;
  bf16x8 qreg[2];
  qreg[0] = *(const bf16x8*)(Qg);
  qreg[1] = *(const bf16x8*)(Qg + 32);

  f32x4 oacc[4];  // [md d-16]; O^T: q=l16, d=quad*4+reg
  f32x4 lacc = (f32x4){0.f, 0.f, 0.f, 0.f};  // ones·P = denominator
#pragma unroll
  for (int md = 0; md < 4; md++) oacc[md] = (f32x4){0.f, 0.f, 0.f, 0.f};

  const int njj = (qt + 2) >> 1;  // 128-wide tiles covering cols 0..q0+63
  for (int jj = 0; jj < njj; jj++) {
    const int j0 = jj * 128;
    __syncthreads();  // prior iter's Ks/Vts reads complete
    const bf16* Kg = Kb + ((size_t)bh * 2048 + j0) * 64;
#pragma unroll
    for (int c = t; c < 1024; c += 256) {
      const int row = c >> 3, pos = c & 7;
      gl_lds16(Kg + (row * 8 + (pos ^ (row & 7))) * 8, Ks + c * 8);
    }
    const bf16* Vg = Vt + (size_t)bh * 64 * 2048 + j0;
#pragma unroll
    for (int c = t; c < 1024; c += 256) {
      const int d = c >> 4, pos = c & 15;
      gl_lds16(Vg + (size_t)d * 2048 + ((pos ^ (d & 15)) * 8), Vts + c * 8);
    }
    __syncthreads();  // staging visible

    // ---- S^T = K Q^T : A=K[s][d] (M=128), B=Q^T[d][q] (N=16 of wave) ----
    f32x4 sacc[8];  // [mt s-16];  C-layout: q=l16, s=quad*4+reg
#pragma unroll
    for (int mt = 0; mt < 8; mt++) sacc[mt] = (f32x4){0.f, 0.f, 0.f, 0.f};
#pragma unroll
    for (int kk = 0; kk < 2; kk++) {
#pragma unroll
      for (int mt = 0; mt < 8; mt++) {
        const int row = mt * 16 + l16;
        const int pos = (kk * 4 + quad) ^ (l16 & 7);  // row&7 == l16&7
        bf16x8 kf = *(const bf16x8*)(Ks + row * 64 + pos * 8);
        sacc[mt] = MFMA16(kf, qreg[kk], sacc[mt], 0, 0, 0);
      }
    }

    // ---- P^T = exp(S^T) packed via v_perm (B-frag layout) ----
    bf16x4 pfrag[8];      // [kt = s-16-block]
    if (jj == njj - 1) {  // wave-uniform: only the last tile masks
#pragma unroll
      for (int mt = 0; mt < 8; mt++) {
        unsigned rb[4];
#pragma unroll
        for (int r2 = 0; r2 < 4; r2++) {
          const int sg = j0 + mt * 16 + quad * 4 + r2;
          const float p = (sg <= qrow) ? __expf(sacc[mt][r2]) : 0.f;
          rb[r2] = __builtin_bit_cast(unsigned, p) + 0x8000u;
        }
        i32x2 pk;
        pk.x = (int)__builtin_amdgcn_perm(rb[1], rb[0], 0x07060302u);
        pk.y = (int)__builtin_amdgcn_perm(rb[3], rb[2], 0x07060302u);
        pfrag[mt] = __builtin_bit_cast(bf16x4, pk);
      }
    } else {
#pragma unroll
      for (int mt = 0; mt < 8; mt++) {
        unsigned rb[4];
#pragma unroll
        for (int r2 = 0; r2 < 4; r2++) {
          const float p = __expf(sacc[mt][r2]);
          rb[r2] = __builtin_bit_cast(unsigned, p) + 0x8000u;
        }
        i32x2 pk;
        pk.x = (int)__builtin_amdgcn_perm(rb[1], rb[0], 0x07060302u);
        pk.y = (int)__builtin_amdgcn_perm(rb[3], rb[2], 0x07060302u);
        pfrag[mt] = __builtin_bit_cast(bf16x4, pk);
      }
    }

    // ---- O^T += V^T P^T ; lacc += ones·P^T (denominator in MFMA pipe) ----
#pragma unroll
    for (int kt = 0; kt < 8; kt++) {
      lacc = MFMA16K16(ones, pfrag[kt], lacc, 0, 0, 0);
#pragma unroll
      for (int md = 0; md < 4; md++) {
        const int d = md * 16 + l16;
        const int pos = (kt * 2 + (quad >> 1)) ^ l16;  // d&15 == l16
        bf16x4 va = *(const bf16x4*)(Vts + d * 128 + pos * 8 + (quad & 1) * 4);
        oacc[md] = MFMA16K16(va, pfrag[kt], oacc[md], 0, 0, 0);
      }
    }
  }

  // ---- epilogue: every lane holds its q's full denominator ----
  const float inv = 1.0f / lacc[0];
#pragma unroll
  for (int md = 0; md < 4; md++) {
    bf16x4 o4;
#pragma unroll
    for (int r2 = 0; r2 < 4; r2++) o4[r2] = f2bf(oacc[md][r2] * inv);
    *(bf16x4*)(attn + ((size_t)b * 2048 + qrow) * 1024 + h * 64 + md * 16 +
               quad * 4) = o4;
  }
}

// ---------------------------------------------------------------------------
// Kernel 3: out = attn @ Wout^T (fp32 output). 128x64 tiles -> grid (32,16).
// R18: BK=128 (R17's BK=64 gained ~3us on this 2-blocks/CU kernel — lowest
// residency benefits most from barrier amortization). Swizzle extends to 16
// chunks/row: pos^(row&15) on stage, ci=(kk2*4+quad)^l16 on read (same bank
// algebra mod 8 as the validated BK=64 case). LDS 48KB; grid already 2/CU
// so no occupancy loss (m132 caveat doesn't bind). 8 K-iterations.
// ---------------------------------------------------------------------------
__global__ __launch_bounds__(256) void out_gemm(
    const bf16* __restrict__ attn, const bf16* __restrict__ Wout,
    float* __restrict__ out) {
  __shared__ bf16 As[128 * 128];
  __shared__ bf16 Bs[64 * 128];
  f32x4 acc[4][2];
#pragma unroll
  for (int i = 0; i < 4; i++)
#pragma unroll
    for (int j = 0; j < 2; j++) acc[i][j] = (f32x4){0.f, 0.f, 0.f, 0.f};
  const int bm = blockIdx.x, bn = blockIdx.y;
  const int t = threadIdx.x, w = t >> 6, l = t & 63;
  const int quad = l >> 4, l16 = l & 15;
  const int wm = (w >> 1) * 64, wn = (w & 1) * 32;
  for (int k0 = 0; k0 < 1024; k0 += 128) {
    __syncthreads();
#pragma unroll
    for (int ii = 0; ii < 8; ii++) {  // A: 128 rows x 16 chunks = 2048
      const int c = t + ii * 256;
      const int row = c >> 4, pos = c & 15;
      gl_lds16(attn + (size_t)(bm * 128 + row) * 1024 + k0 +
                   ((pos ^ (row & 15)) * 8),
               As + c * 8);
    }
#pragma unroll
    for (int ii = 0; ii < 4; ii++) {  // B: 64 rows x 16 chunks = 1024
      const int c = t + ii * 256;
      const int row = c >> 4, pos = c & 15;
      gl_lds16(Wout + (size_t)(bn * 64 + row) * 1024 + k0 +
                   ((pos ^ (row & 15)) * 8),
               Bs + c * 8);
    }
    __syncthreads();
#pragma unroll
    for (int kk2 = 0; kk2 < 4; kk2++) {
      bf16x8 af[4], bg[2];
#pragma unroll
      for (int i = 0; i < 4; i++) {
        const int rr = wm + i * 16 + l16;  // rr&15 == l16
        const int ci = (kk2 * 4 + quad) ^ l16;
        af[i] = *(const bf16x8*)(As + rr * 128 + ci * 8);
      }
#pragma unroll
      for (int j = 0; j < 2; j++) {
        const int rr = wn + j * 16 + l16;
        const int ci = (kk2 * 4 + quad) ^ l16;
        bg[j] = *(const bf16x8*)(Bs + rr * 128 + ci * 8);
      }
#pragma unroll
      for (int i = 0; i < 4; i++)
#pragma unroll
        for (int j = 0; j < 2; j++)
          acc[i][j] = MFMA16(af[i], bg[j], acc[i][j], 0, 0, 0);
    }
  }
#pragma unroll
  for (int i = 0; i < 4; i++) {
#pragma unroll
    for (int j = 0; j < 2; j++) {
      const int n = bn * 64 + wn + j * 16 + l16;
#pragma unroll
      for (int r = 0; r < 4; r++) {
        const int m = bm * 128 + wm + i * 16 + quad * 4 + r;
        out[(size_t)m * 1024 + n] = acc[i][j][r];
      }
    }
  }
}

// ---------------------------------------------------------------------------
extern "C" void kernel_launch(void* const* d_in, const int* in_sizes, int n_in,
                              void* d_out, int out_size, void* d_ws, size_t ws_size,
                              hipStream_t stream) {
  const float* x = (const float*)d_in[0];      // [2,2048,1024] fp32
  const float* Wqkv = (const float*)d_in[1];   // [3072,1024]   fp32
  const float* Wout = (const float*)d_in[2];   // [1024,1024]   fp32
  float* out = (float*)d_out;                  // [2,2048,1024] fp32

  char* ws = (char*)d_ws;
  const size_t MB = 1024 * 1024;
  bf16* xb = (bf16*)(ws + 0 * MB);      // [4096][1024]  8 MB (consumed by qkv)
  bf16* at = (bf16*)(ws + 0 * MB);      // [4096][1024]  8 MB (alias, after qkv)
  bf16* Wqkvb = (bf16*)(ws + 8 * MB);   // [3072][1024]  6 MB
  bf16* Woutb = (bf16*)(ws + 14 * MB);  // [1024][1024]  2 MB
  bf16* Qb = (bf16*)(ws + 16 * MB);     // [32][2048][64] 8 MB (pre-scaled)
  bf16* Kb = (bf16*)(ws + 24 * MB);     // [32][2048][64] 8 MB
  bf16* Vt = (bf16*)(ws + 32 * MB);     // [32][64][2048] 8 MB

  cvt_all<<<2048, 256, 0, stream>>>(x, Wqkv, Wout, xb, Wqkvb, Woutb);
  qkv_gemm<<<dim3(32, 24), 256, 0, stream>>>(xb, Wqkvb, Qb, Kb, Vt);
  attn_kernel<<<1024, 256, 0, stream>>>(Qb, Kb, Vt, at);
  out_gemm<<<dim3(32, 16), 256, 0, stream>>>(at, Woutb, out);
}

// Round 19
// 155.314 us; speedup vs baseline: 1.1086x; 1.0237x over previous
//
#include <hip/hip_runtime.h>
#include <hip/hip_bf16.h>
#include <math.h>

using bf16 = __hip_bfloat16;
typedef __attribute__((ext_vector_type(8))) short bf16x8;
typedef __attribute__((ext_vector_type(4))) short bf16x4;
typedef __attribute__((ext_vector_type(4))) float f32x4;
typedef __attribute__((ext_vector_type(2))) int i32x2;

// async global->LDS, 16B per lane (guide §5: width=16 is the m93->m97 2x step)
static __device__ __forceinline__ void gl_lds16(const void* g, void* l) {
  __builtin_amdgcn_global_load_lds(
      (const __attribute__((address_space(1))) unsigned int*)g,
      (__attribute__((address_space(3))) unsigned int*)l, 16, 0, 0);
}

#define MFMA16 __builtin_amdgcn_mfma_f32_16x16x32_bf16
#define MFMA16K16 __builtin_amdgcn_mfma_f32_16x16x16bf16_1k

// fast f32->bf16 (round-to-nearest-ish; fine for p in [0,1] and O outputs)
static __device__ __forceinline__ short f2bf(float f) {
  return (short)((__builtin_bit_cast(unsigned int, f) + 0x8000u) >> 16);
}

// ---------------------------------------------------------------------------
// Kernel 0: fp32 -> bf16 for all three inputs in ONE launch.
// R18: 16 floats/thread, 2x16B stores. grid 2048: [0,1024) x,
// [1024,1792) Wqkv, [1792,2048) Wout.
// ---------------------------------------------------------------------------
__global__ __launch_bounds__(256) void cvt_all(
    const float* __restrict__ x, const float* __restrict__ wqkv,
    const float* __restrict__ wout, bf16* __restrict__ xb,
    bf16* __restrict__ wqkvb, bf16* __restrict__ woutb) {
  const int blk = blockIdx.x;
  const float* src;
  bf16* dst;
  int base;
  if (blk < 1024) {
    src = x; dst = xb; base = blk;
  } else if (blk < 1792) {
    src = wqkv; dst = wqkvb; base = blk - 1024;
  } else {
    src = wout; dst = woutb; base = blk - 1792;
  }
  const int i = (base * 256 + threadIdx.x) * 16;
#pragma unroll
  for (int half = 0; half < 2; half++) {
    const float4 v0 = *(const float4*)(src + i + half * 8);
    const float4 v1 = *(const float4*)(src + i + half * 8 + 4);
    bf16x8 o;
    o[0] = f2bf(v0.x);
    o[1] = f2bf(v0.y);
    o[2] = f2bf(v0.z);
    o[3] = f2bf(v0.w);
    o[4] = f2bf(v1.x);
    o[5] = f2bf(v1.y);
    o[6] = f2bf(v1.z);
    o[7] = f2bf(v1.w);
    *(bf16x8*)(dst + i + half * 8) = o;
  }
}

// ---------------------------------------------------------------------------
// 128x128 block of C[m,n] = sum_k A[m,k]*B[n,k]   (A:[*,K] row-major, B:[*,K])
// R14: BK=64, XOR-swizzled LDS (pos^(row&7)) on both stage-source and read.
// ---------------------------------------------------------------------------
template <int K>
static __device__ __forceinline__ void gemm_bt_acc(
    const bf16* __restrict__ A, const bf16* __restrict__ B,
    int rowA0, int rowB0, bf16* As, bf16* Bs, f32x4 acc[4][4]) {
  const int t = threadIdx.x;
  const int w = t >> 6, l = t & 63;
  const int quad = l >> 4, l16 = l & 15;
  const int wm = (w >> 1) * 64, wn = (w & 1) * 64;
  for (int k0 = 0; k0 < K; k0 += 64) {
    __syncthreads();
#pragma unroll
    for (int ii = 0; ii < 4; ii++) {
      const int c = t + ii * 256;  // 0..1023: row = c>>3 (128B rows), pos 0..7
      const int row = c >> 3, pos = c & 7;
      const size_t off = (size_t)row * K + k0 + ((pos ^ (row & 7)) * 8);
      gl_lds16(A + (size_t)rowA0 * K + off, As + c * 8);
      gl_lds16(B + (size_t)rowB0 * K + off, Bs + c * 8);
    }
    __syncthreads();
#pragma unroll
    for (int kk2 = 0; kk2 < 2; kk2++) {
      bf16x8 af[4], bg[4];
#pragma unroll
      for (int i = 0; i < 4; i++) {
        const int rr = wm + i * 16 + l16;  // rr&7 == l16&7
        const int ci = (kk2 * 4 + quad) ^ (l16 & 7);
        af[i] = *(const bf16x8*)(As + rr * 64 + ci * 8);
      }
#pragma unroll
      for (int j = 0; j < 4; j++) {
        const int rr = wn + j * 16 + l16;
        const int ci = (kk2 * 4 + quad) ^ (l16 & 7);
        bg[j] = *(const bf16x8*)(Bs + rr * 64 + ci * 8);
      }
#pragma unroll
      for (int i = 0; i < 4; i++)
#pragma unroll
        for (int j = 0; j < 4; j++)
          acc[i][j] = MFMA16(af[i], bg[j], acc[i][j], 0, 0, 0);
    }
  }
}

// ---------------------------------------------------------------------------
// Kernel 1: qkv = x @ Wqkv^T ; scatter Q*(0.125*log2e) — R19: softmax scale
// and the exp->exp2 conversion folded into one fp32 constant so attn's
// softmax needs only v_exp_f32 (no per-element v_mul). K, Vt unchanged.
// Grid dim3(32,24): default order is XCD-optimal (XCD = bm%8).
// ---------------------------------------------------------------------------
__global__ __launch_bounds__(256, 3) void qkv_gemm(
    const bf16* __restrict__ x, const bf16* __restrict__ Wqkv,
    bf16* __restrict__ Qb, bf16* __restrict__ Kb, bf16* __restrict__ Vt) {
  __shared__ bf16 As[128 * 64];
  __shared__ bf16 Bs[128 * 64];
  f32x4 acc[4][4];
#pragma unroll
  for (int i = 0; i < 4; i++)
#pragma unroll
    for (int j = 0; j < 4; j++) acc[i][j] = (f32x4){0.f, 0.f, 0.f, 0.f};
  const int bm = blockIdx.x, bn = blockIdx.y;
  gemm_bt_acc<1024>(x, Wqkv, bm * 128, bn * 128, As, Bs, acc);

  const int t = threadIdx.x, w = t >> 6, l = t & 63;
  const int quad = l >> 4, l16 = l & 15;
  const int wm = (w >> 1) * 64, wn = (w & 1) * 64;
#pragma unroll
  for (int i = 0; i < 4; i++) {
    const int m0 = bm * 128 + wm + i * 16 + quad * 4;  // 4 contiguous m (=s)
    const int b = m0 >> 11, s0 = m0 & 2047;            // same b for all 4 r
#pragma unroll
    for (int j = 0; j < 4; j++) {
      const int n = bn * 128 + wn + j * 16 + l16;  // 0..3071
      const int which = n >> 10;
      const int nn = n & 1023;
      const int h = nn >> 6, d = nn & 63;
      const int bh = b * 16 + h;
      if (which == 2) {  // V: contiguous s -> one vectorized store
        bf16x4 v4;
#pragma unroll
        for (int r = 0; r < 4; r++)
          v4[r] = (short)__builtin_bit_cast(unsigned short,
                                            __float2bfloat16(acc[i][j][r]));
        *(bf16x4*)(Vt + ((size_t)bh * 64 + d) * 2048 + s0) = v4;
      } else {
        // 0.125 * log2(e): softmax scale + exp->exp2 fold (fp32 multiply
        // before the bf16 round — same relative error as 0.125).
        const float sc = (which == 0) ? 0.18033688011112042f : 1.0f;
        bf16* dst = (which == 0) ? Qb : Kb;
#pragma unroll
        for (int r = 0; r < 4; r++)
          dst[((size_t)bh * 2048 + s0 + r) * 64 + d] =
              __float2bfloat16(acc[i][j][r] * sc);
      }
    }
  }
}

// ---------------------------------------------------------------------------
// Kernel 2: causal flash attention — R6 structure EXACTLY (42.0us).
// R19: exp2-ONLY diet — __builtin_amdgcn_exp2f replaces __expf (log2e is
// pre-folded into Q by qkv). This removes 32 v_mul/tile. R10-12's failure
// bundled this with inline-asm cvt_pk (the spill trigger, rule #19/#20);
// exp2-alone uses a plain intrinsic, perm-pack unchanged. Tripwire:
// WRITE_SIZE must stay 8MB (spill shows as phantom writes).
// ---------------------------------------------------------------------------
__global__ __launch_bounds__(256, 4) void attn_kernel(
    const bf16* __restrict__ Qb, const bf16* __restrict__ Kb,
    const bf16* __restrict__ Vt, bf16* __restrict__ attn) {
  __shared__ bf16 Ks[128 * 64];   // [krow][d]  swizzled (8 chunks/row)
  __shared__ bf16 Vts[64 * 128];  // [d][s]     swizzled (16 chunks/row)
  const int x = blockIdx.x;
  const int bh = x & 31;
  const int T = x >> 5;  // 0..31
  const int s = T >> 3, r = T & 7;
  const int qt = s * 8 + ((s & 1) ? 7 - r : r);  // balanced resident sets
  const int q0 = qt * 64;
  const int t = threadIdx.x, w = t >> 6, l = t & 63;
  const int quad = l >> 4, l16 = l & 15;
  const bf16x4 ones = {16256, 16256, 16256, 16256};  // bf16 1.0 x4
  const int b = bh >> 4, h = bh & 15;

  // ---- Q into registers: lane holds Q[q=qrow][d=kk*32+quad*8+e] ----
  const int qrow = q0 + w * 16 + l16;
  const bf16* Qg = Qb + ((size_t)bh * 2048 + qrow) * 64 + quad * 8;
  bf16x8 qreg[2];
  qreg[0] = *(const bf16x8*)(Qg);
  qreg[1] = *(const bf16x8*)(Qg + 32);

  f32x4 oacc[4];  // [md d-16]; O^T: q=l16, d=quad*4+reg
  f32x4 lacc = (f32x4){0.f, 0.f, 0.f, 0.f};  // ones·P = denominator
#pragma unroll
  for (int md = 0; md < 4; md++) oacc[md] = (f32x4){0.f, 0.f, 0.f, 0.f};

  const int njj = (qt + 2) >> 1;  // 128-wide tiles covering cols 0..q0+63
  for (int jj = 0; jj < njj; jj++) {
    const int j0 = jj * 128;
    __syncthreads();  // prior iter's Ks/Vts reads complete
    const bf16* Kg = Kb + ((size_t)bh * 2048 + j0) * 64;
#pragma unroll
    for (int c = t; c < 1024; c += 256) {
      const int row = c >> 3, pos = c & 7;
      gl_lds16(Kg + (row * 8 + (pos ^ (row & 7))) * 8, Ks + c * 8);
    }
    const bf16* Vg = Vt + (size_t)bh * 64 * 2048 + j0;
#pragma unroll
    for (int c = t; c < 1024; c += 256) {
      const int d = c >> 4, pos = c & 15;
      gl_lds16(Vg + (size_t)d * 2048 + ((pos ^ (d & 15)) * 8), Vts + c * 8);
    }
    __syncthreads();  // staging visible

    // ---- S^T = K Q^T : A=K[s][d] (M=128), B=Q^T[d][q] (N=16 of wave) ----
    f32x4 sacc[8];  // [mt s-16];  C-layout: q=l16, s=quad*4+reg
#pragma unroll
    for (int mt = 0; mt < 8; mt++) sacc[mt] = (f32x4){0.f, 0.f, 0.f, 0.f};
#pragma unroll
    for (int kk = 0; kk < 2; kk++) {
#pragma unroll
      for (int mt = 0; mt < 8; mt++) {
        const int row = mt * 16 + l16;
        const int pos = (kk * 4 + quad) ^ (l16 & 7);  // row&7 == l16&7
        bf16x8 kf = *(const bf16x8*)(Ks + row * 64 + pos * 8);
        sacc[mt] = MFMA16(kf, qreg[kk], sacc[mt], 0, 0, 0);
      }
    }

    // ---- P^T = exp2(S^T) packed via v_perm (B-frag layout) ----
    bf16x4 pfrag[8];      // [kt = s-16-block]
    if (jj == njj - 1) {  // wave-uniform: only the last tile masks
#pragma unroll
      for (int mt = 0; mt < 8; mt++) {
        unsigned rb[4];
#pragma unroll
        for (int r2 = 0; r2 < 4; r2++) {
          const int sg = j0 + mt * 16 + quad * 4 + r2;
          const float p =
              (sg <= qrow) ? __builtin_amdgcn_exp2f(sacc[mt][r2]) : 0.f;
          rb[r2] = __builtin_bit_cast(unsigned, p) + 0x8000u;
        }
        i32x2 pk;
        pk.x = (int)__builtin_amdgcn_perm(rb[1], rb[0], 0x07060302u);
        pk.y = (int)__builtin_amdgcn_perm(rb[3], rb[2], 0x07060302u);
        pfrag[mt] = __builtin_bit_cast(bf16x4, pk);
      }
    } else {
#pragma unroll
      for (int mt = 0; mt < 8; mt++) {
        unsigned rb[4];
#pragma unroll
        for (int r2 = 0; r2 < 4; r2++) {
          const float p = __builtin_amdgcn_exp2f(sacc[mt][r2]);
          rb[r2] = __builtin_bit_cast(unsigned, p) + 0x8000u;
        }
        i32x2 pk;
        pk.x = (int)__builtin_amdgcn_perm(rb[1], rb[0], 0x07060302u);
        pk.y = (int)__builtin_amdgcn_perm(rb[3], rb[2], 0x07060302u);
        pfrag[mt] = __builtin_bit_cast(bf16x4, pk);
      }
    }

    // ---- O^T += V^T P^T ; lacc += ones·P^T (denominator in MFMA pipe) ----
#pragma unroll
    for (int kt = 0; kt < 8; kt++) {
      lacc = MFMA16K16(ones, pfrag[kt], lacc, 0, 0, 0);
#pragma unroll
      for (int md = 0; md < 4; md++) {
        const int d = md * 16 + l16;
        const int pos = (kt * 2 + (quad >> 1)) ^ l16;  // d&15 == l16
        bf16x4 va = *(const bf16x4*)(Vts + d * 128 + pos * 8 + (quad & 1) * 4);
        oacc[md] = MFMA16K16(va, pfrag[kt], oacc[md], 0, 0, 0);
      }
    }
  }

  // ---- epilogue: every lane holds its q's full denominator ----
  const float inv = 1.0f / lacc[0];
#pragma unroll
  for (int md = 0; md < 4; md++) {
    bf16x4 o4;
#pragma unroll
    for (int r2 = 0; r2 < 4; r2++) o4[r2] = f2bf(oacc[md][r2] * inv);
    *(bf16x4*)(attn + ((size_t)b * 2048 + qrow) * 1024 + h * 64 + md * 16 +
               quad * 4) = o4;
  }
}

// ---------------------------------------------------------------------------
// Kernel 3: out = attn @ Wout^T (fp32 output). 128x64 tiles -> grid (32,16).
// R18: BK=128, swizzle pos^(row&15) stage / ci^l16 read. LDS 48KB, 2/CU.
// ---------------------------------------------------------------------------
__global__ __launch_bounds__(256) void out_gemm(
    const bf16* __restrict__ attn, const bf16* __restrict__ Wout,
    float* __restrict__ out) {
  __shared__ bf16 As[128 * 128];
  __shared__ bf16 Bs[64 * 128];
  f32x4 acc[4][2];
#pragma unroll
  for (int i = 0; i < 4; i++)
#pragma unroll
    for (int j = 0; j < 2; j++) acc[i][j] = (f32x4){0.f, 0.f, 0.f, 0.f};
  const int bm = blockIdx.x, bn = blockIdx.y;
  const int t = threadIdx.x, w = t >> 6, l = t & 63;
  const int quad = l >> 4, l16 = l & 15;
  const int wm = (w >> 1) * 64, wn = (w & 1) * 32;
  for (int k0 = 0; k0 < 1024; k0 += 128) {
    __syncthreads();
#pragma unroll
    for (int ii = 0; ii < 8; ii++) {  // A: 128 rows x 16 chunks = 2048
      const int c = t + ii * 256;
      const int row = c >> 4, pos = c & 15;
      gl_lds16(attn + (size_t)(bm * 128 + row) * 1024 + k0 +
                   ((pos ^ (row & 15)) * 8),
               As + c * 8);
    }
#pragma unroll
    for (int ii = 0; ii < 4; ii++) {  // B: 64 rows x 16 chunks = 1024
      const int c = t + ii * 256;
      const int row = c >> 4, pos = c & 15;
      gl_lds16(Wout + (size_t)(bn * 64 + row) * 1024 + k0 +
                   ((pos ^ (row & 15)) * 8),
               Bs + c * 8);
    }
    __syncthreads();
#pragma unroll
    for (int kk2 = 0; kk2 < 4; kk2++) {
      bf16x8 af[4], bg[2];
#pragma unroll
      for (int i = 0; i < 4; i++) {
        const int rr = wm + i * 16 + l16;  // rr&15 == l16
        const int ci = (kk2 * 4 + quad) ^ l16;
        af[i] = *(const bf16x8*)(As + rr * 128 + ci * 8);
      }
#pragma unroll
      for (int j = 0; j < 2; j++) {
        const int rr = wn + j * 16 + l16;
        const int ci = (kk2 * 4 + quad) ^ l16;
        bg[j] = *(const bf16x8*)(Bs + rr * 128 + ci * 8);
      }
#pragma unroll
      for (int i = 0; i < 4; i++)
#pragma unroll
        for (int j = 0; j < 2; j++)
          acc[i][j] = MFMA16(af[i], bg[j], acc[i][j], 0, 0, 0);
    }
  }
#pragma unroll
  for (int i = 0; i < 4; i++) {
#pragma unroll
    for (int j = 0; j < 2; j++) {
      const int n = bn * 64 + wn + j * 16 + l16;
#pragma unroll
      for (int r = 0; r < 4; r++) {
        const int m = bm * 128 + wm + i * 16 + quad * 4 + r;
        out[(size_t)m * 1024 + n] = acc[i][j][r];
      }
    }
  }
}

// ---------------------------------------------------------------------------
extern "C" void kernel_launch(void* const* d_in, const int* in_sizes, int n_in,
                              void* d_out, int out_size, void* d_ws, size_t ws_size,
                              hipStream_t stream) {
  const float* x = (const float*)d_in[0];      // [2,2048,1024] fp32
  const float* Wqkv = (const float*)d_in[1];   // [3072,1024]   fp32
  const float* Wout = (const float*)d_in[2];   // [1024,1024]   fp32
  float* out = (float*)d_out;                  // [2,2048,1024] fp32

  char* ws = (char*)d_ws;
  const size_t MB = 1024 * 1024;
  bf16* xb = (bf16*)(ws + 0 * MB);      // [4096][1024]  8 MB (consumed by qkv)
  bf16* at = (bf16*)(ws + 0 * MB);      // [4096][1024]  8 MB (alias, after qkv)
  bf16* Wqkvb = (bf16*)(ws + 8 * MB);   // [3072][1024]  6 MB
  bf16* Woutb = (bf16*)(ws + 14 * MB);  // [1024][1024]  2 MB
  bf16* Qb = (bf16*)(ws + 16 * MB);     // [32][2048][64] 8 MB (pre-scaled)
  bf16* Kb = (bf16*)(ws + 24 * MB);     // [32][2048][64] 8 MB
  bf16* Vt = (bf16*)(ws + 32 * MB);     // [32][64][2048] 8 MB

  cvt_all<<<2048, 256, 0, stream>>>(x, Wqkv, Wout, xb, Wqkvb, Woutb);
  qkv_gemm<<<dim3(32, 24), 256, 0, stream>>>(xb, Wqkvb, Qb, Kb, Vt);
  attn_kernel<<<1024, 256, 0, stream>>>(Qb, Kb, Vt, at);
  out_gemm<<<dim3(32, 16), 256, 0, stream>>>(at, Woutb, out);
}